// Round 1
// 676.355 us; speedup vs baseline: 1.1852x; 1.1852x over previous
//
#include <hip/hip_runtime.h>

// Qwen3 MoE single-expert FFN on MI355X (gfx950).
// out = silu(H @ G_e^T) * (H @ U_e^T) @ D_e^T
// M=32768, HIDDEN=1024, INTER=768. All fp32 in/out; compute in bf16 MFMA
// (threshold 1.55e-2 admits bf16-level error).
//
// R1: gemm_gateup re-tiled BM=128 x BN=64 (was 128x128). The fused kernel's
// dual accumulator (accg+accu = 128 AGPRs) on top of ~160 VGPRs exceeded the
// 256-reg/wave budget for 2 waves/SIMD on the unified gfx950 RF -> 1 block/CU
// (OccupancyPercent 11.5%), fully exposing every barrier drain (MfmaUtil 17%).
// BN=64 halves acc to 64 AGPRs and fragments to 32 VGPRs; per-K-step mix is
// now 16 MFMA : 8 ds_read_b128 : 4 global_load_lds == the proven m97 ratios.

typedef __bf16 bf16;
typedef bf16 bf16x8 __attribute__((ext_vector_type(8)));
typedef bf16 bf16x4 __attribute__((ext_vector_type(4)));
typedef float f32x4 __attribute__((ext_vector_type(4)));

static constexpr int M_TOK  = 32768;
static constexpr int HIDDEN = 1024;
static constexpr int INTER  = 768;

#define BM 128
#define BN 128   // down-GEMM N-tile
#define BNG 64   // gate/up fused kernel N-tile
#define BK 32

// ---------------------------------------------------------------- casts ----

__global__ __launch_bounds__(256) void cast_h_kernel(const float* __restrict__ in,
                                                     bf16* __restrict__ out) {
    int i = blockIdx.x * 256 + threadIdx.x;      // one float4 per thread, exact grid
    f32x4 v = ((const f32x4*)in)[i];
    bf16x4 o;
    o.x = (bf16)v.x; o.y = (bf16)v.y; o.z = (bf16)v.z; o.w = (bf16)v.w;
    ((bf16x4*)out)[i] = o;
}

__global__ __launch_bounds__(256) void cast_w_kernel(const float* __restrict__ G,
                                                     const float* __restrict__ U,
                                                     const float* __restrict__ D,
                                                     const int* __restrict__ eidx,
                                                     bf16* __restrict__ Gb,
                                                     bf16* __restrict__ Ub,
                                                     bf16* __restrict__ Db) {
    const int e = *eidx;
    const int EW4 = (INTER * HIDDEN) / 4;        // 196608 float4s per expert matrix
    int i = blockIdx.x * 256 + threadIdx.x;
    if (i >= 3 * EW4) return;
    int which = i / EW4;
    int r = i - which * EW4;
    const float* src = (which == 0) ? G : (which == 1) ? U : D;
    bf16* dst = (which == 0) ? Gb : (which == 1) ? Ub : Db;
    f32x4 v = ((const f32x4*)(src + (size_t)e * (INTER * HIDDEN)))[r];
    bf16x4 o;
    o.x = (bf16)v.x; o.y = (bf16)v.y; o.z = (bf16)v.z; o.w = (bf16)v.w;
    ((bf16x4*)dst)[r] = o;
}

// ------------------------------------------------- fused gate+up GEMM ------
// A:[M,K=1024] bf16, G/U:[N=768,K] bf16 (NT). h = silu(A G^T) * (A U^T), bf16.
// Tile: 128x64, 4 waves (2M x 2N), per-wave 64x32 of BOTH g and u.

__global__ __launch_bounds__(256, 2) void gemm_gateup(const bf16* __restrict__ A,
                                                      const bf16* __restrict__ G,
                                                      const bf16* __restrict__ U,
                                                      bf16* __restrict__ Hout) {
    const int K = HIDDEN;     // 1024
    const int N = INTER;      // 768
    __shared__ bf16 sA[BM * BK];    // 128x32 = 8 KB
    __shared__ bf16 sG[BNG * BK];   //  64x32 = 4 KB
    __shared__ bf16 sU[BNG * BK];   //  64x32 = 4 KB

    const int t    = threadIdx.x;
    const int wave = t >> 6;
    const int lane = t & 63;
    const int wr   = wave >> 1;   // wave row (0/1) -> 64-row strip
    const int wc   = wave & 1;    // wave col (0/1) -> 32-col strip
    const int m0   = blockIdx.x * BM;
    const int n0   = blockIdx.y * BNG;

    // staging addressing: row = wave*16 + lane/4 (covers 64 rows / issue),
    // col = (lane&3)*8; LDS dest must be linear in lane (global_load_lds).
    const int srow = wave * 16 + (lane >> 2);
    const int scol = (lane & 3) * 8;
    const int ldsOff = wave * 512 + lane * 8;     // elements; == (srow*BK + scol)

    f32x4 accg[4][2];
    f32x4 accu[4][2];
#pragma unroll
    for (int i = 0; i < 4; i++)
#pragma unroll
        for (int j = 0; j < 2; j++) {
            accg[i][j] = (f32x4){0.f, 0.f, 0.f, 0.f};
            accu[i][j] = (f32x4){0.f, 0.f, 0.f, 0.f};
        }

    const bf16* pA = A + (size_t)(m0 + srow) * K + scol;
    const bf16* pG = G + (size_t)(n0 + srow) * K + scol;
    const bf16* pU = U + (size_t)(n0 + srow) * K + scol;

    for (int kt = 0; kt < K; kt += BK) {
#pragma unroll
        for (int j = 0; j < 2; ++j) {
            __builtin_amdgcn_global_load_lds(
                (const __attribute__((address_space(1))) void*)(pA + (size_t)j * 64 * K + kt),
                (__attribute__((address_space(3))) void*)(sA + j * 2048 + ldsOff), 16, 0, 0);
        }
        __builtin_amdgcn_global_load_lds(
            (const __attribute__((address_space(1))) void*)(pG + kt),
            (__attribute__((address_space(3))) void*)(sG + ldsOff), 16, 0, 0);
        __builtin_amdgcn_global_load_lds(
            (const __attribute__((address_space(1))) void*)(pU + kt),
            (__attribute__((address_space(3))) void*)(sU + ldsOff), 16, 0, 0);
        __syncthreads();   // compiler emits vmcnt(0) drain before s_barrier

        bf16x8 af[4], gf[2], uf[2];
        const int fk = (lane >> 4) * 8;
        const int fr = lane & 15;
#pragma unroll
        for (int i = 0; i < 4; i++)
            af[i] = *(const bf16x8*)(sA + (wr * 64 + i * 16 + fr) * BK + fk);
#pragma unroll
        for (int j = 0; j < 2; j++) {
            gf[j] = *(const bf16x8*)(sG + (wc * 32 + j * 16 + fr) * BK + fk);
            uf[j] = *(const bf16x8*)(sU + (wc * 32 + j * 16 + fr) * BK + fk);
        }
#pragma unroll
        for (int i = 0; i < 4; i++)
#pragma unroll
            for (int j = 0; j < 2; j++) {
                accg[i][j] = __builtin_amdgcn_mfma_f32_16x16x32_bf16(af[i], gf[j], accg[i][j], 0, 0, 0);
                accu[i][j] = __builtin_amdgcn_mfma_f32_16x16x32_bf16(af[i], uf[j], accu[i][j], 0, 0, 0);
            }
        __syncthreads();
    }

    // epilogue: silu(g)*u, store bf16. C/D layout: col=lane&15, row=(lane>>4)*4+reg
    const int crow = (lane >> 4) * 4;
    const int ccol = lane & 15;
#pragma unroll
    for (int i = 0; i < 4; i++)
#pragma unroll
        for (int j = 0; j < 2; j++) {
            int col = n0 + wc * 32 + j * 16 + ccol;
#pragma unroll
            for (int r = 0; r < 4; r++) {
                int row = m0 + wr * 64 + i * 16 + crow + r;
                float g = accg[i][j][r];
                float u = accu[i][j][r];
                float s = g / (1.0f + __expf(-g));
                Hout[(size_t)row * N + col] = (bf16)(s * u);
            }
        }
}

// ------------------------------------------------------- down GEMM ---------
// A:[M,K=768] bf16 (h), B:[N=1024,K=768] bf16 (D_e, NT). out fp32 [M,N].

__global__ __launch_bounds__(256, 2) void gemm_down(const bf16* __restrict__ A,
                                                    const bf16* __restrict__ B,
                                                    float* __restrict__ Out) {
    const int K = INTER;      // 768
    const int N = HIDDEN;     // 1024
    __shared__ bf16 sA[BM * BK];
    __shared__ bf16 sB[BM * BK];

    const int t    = threadIdx.x;
    const int wave = t >> 6;
    const int lane = t & 63;
    const int wr   = wave >> 1;
    const int wc   = wave & 1;
    const int m0   = blockIdx.x * BM;
    const int n0   = blockIdx.y * BN;

    const int srow = wave * 16 + (lane >> 2);
    const int scol = (lane & 3) * 8;
    const int ldsOff = wave * 512 + lane * 8;

    f32x4 acc[4][4];
#pragma unroll
    for (int i = 0; i < 4; i++)
#pragma unroll
        for (int j = 0; j < 4; j++)
            acc[i][j] = (f32x4){0.f, 0.f, 0.f, 0.f};

    const bf16* pA = A + (size_t)(m0 + srow) * K + scol;
    const bf16* pB = B + (size_t)(n0 + srow) * K + scol;

    for (int kt = 0; kt < K; kt += BK) {
#pragma unroll
        for (int j = 0; j < 2; ++j) {
            __builtin_amdgcn_global_load_lds(
                (const __attribute__((address_space(1))) void*)(pA + (size_t)j * 64 * K + kt),
                (__attribute__((address_space(3))) void*)(sA + j * 2048 + ldsOff), 16, 0, 0);
            __builtin_amdgcn_global_load_lds(
                (const __attribute__((address_space(1))) void*)(pB + (size_t)j * 64 * K + kt),
                (__attribute__((address_space(3))) void*)(sB + j * 2048 + ldsOff), 16, 0, 0);
        }
        __syncthreads();

        bf16x8 af[4], bfg[4];
        const int fk = (lane >> 4) * 8;
        const int fr = lane & 15;
#pragma unroll
        for (int i = 0; i < 4; i++) {
            af[i]  = *(const bf16x8*)(sA + (wr * 64 + i * 16 + fr) * BK + fk);
            bfg[i] = *(const bf16x8*)(sB + (wc * 64 + i * 16 + fr) * BK + fk);
        }
#pragma unroll
        for (int i = 0; i < 4; i++)
#pragma unroll
            for (int j = 0; j < 4; j++)
                acc[i][j] = __builtin_amdgcn_mfma_f32_16x16x32_bf16(af[i], bfg[j], acc[i][j], 0, 0, 0);
        __syncthreads();
    }

    const int crow = (lane >> 4) * 4;
    const int ccol = lane & 15;
#pragma unroll
    for (int i = 0; i < 4; i++)
#pragma unroll
        for (int j = 0; j < 4; j++) {
            int col = n0 + wc * 64 + j * 16 + ccol;
#pragma unroll
            for (int r = 0; r < 4; r++) {
                int row = m0 + wr * 64 + i * 16 + crow + r;
                Out[(size_t)row * N + col] = acc[i][j][r];
            }
        }
}

// ------------------------------------------------------------- launch ------

extern "C" void kernel_launch(void* const* d_in, const int* in_sizes, int n_in,
                              void* d_out, int out_size, void* d_ws, size_t ws_size,
                              hipStream_t stream) {
    const float* H = (const float*)d_in[0];   // [32768,1024]
    const float* G = (const float*)d_in[1];   // [64,768,1024]
    const float* U = (const float*)d_in[2];   // [64,768,1024]
    const float* D = (const float*)d_in[3];   // [64,1024,768]
    const int* eidx = (const int*)d_in[4];    // scalar
    float* out = (float*)d_out;               // [32768,1024] fp32

    // workspace layout (bytes):
    //   Hb  : 32768*1024*2 = 67108864
    //   Gb  : 768*1024*2   = 1572864
    //   Ub  : 1572864
    //   Db  : 1572864
    //   hb  : 32768*768*2  = 50331648     total ~116.5 MB
    char* ws = (char*)d_ws;
    bf16* Hb = (bf16*)(ws);
    bf16* Gb = (bf16*)(ws + 67108864);
    bf16* Ub = (bf16*)(ws + 67108864 + 1 * 1572864);
    bf16* Db = (bf16*)(ws + 67108864 + 2 * 1572864);
    bf16* hb = (bf16*)(ws + 67108864 + 3 * 1572864);

    // 1) cast H to bf16 : 8388608 float4s -> 32768 blocks x 256
    cast_h_kernel<<<32768, 256, 0, stream>>>(H, Hb);
    // 2) cast selected expert weights : 3*196608 float4s -> 2304 blocks
    cast_w_kernel<<<2304, 256, 0, stream>>>(G, U, D, eidx, Gb, Ub, Db);
    // 3) fused gate/up GEMM + SiLU  (grid: 256 M-tiles x 12 N-tiles of 64)
    dim3 g1(M_TOK / BM, INTER / BNG);
    gemm_gateup<<<g1, 256, 0, stream>>>(Hb, Gb, Ub, hb);
    // 4) down GEMM (grid: 256 M-tiles x 8 N-tiles)
    dim3 g2(M_TOK / BM, HIDDEN / BN);
    gemm_down<<<g2, 256, 0, stream>>>(hb, Db, out);
}